// Round 5
// baseline (2820.740 us; speedup 1.0000x reference)
//
#include <hip/hip_runtime.h>
#include <hip/hip_fp16.h>

typedef _Float16 half8 __attribute__((ext_vector_type(8)));
typedef float floatx4 __attribute__((ext_vector_type(4)));

static constexpr int B_ = 8, D_ = 512, T_ = 2048, K_ = 8192;
static constexpr size_t ZSZ = (size_t)B_ * D_ * T_;   // 8388608 elems; one output segment
static constexpr size_t SEGB = ZSZ * 4;               // 33,554,432 bytes per segment
static constexpr float MARGIN = 0.02f;                // f16 screen err ~4e-3; 2x + slack

// ---------------- prep: transpose z (B,D,T) -> encT (BT,D) in f32 + f16 ----------------
__global__ __launch_bounds__(256) void k_prep_z(const float* __restrict__ z,
                                                float* __restrict__ encT,
                                                _Float16* __restrict__ encTh) {
  int bid = blockIdx.x;
  int db = bid & 7, tb = (bid >> 3) & 31, b = bid >> 8;   // 8 x 32 x 8 = 2048 blocks
  int d0 = db * 64, t0 = tb * 64;
  __shared__ float tz[64][65];
  int tid = threadIdx.x, w = tid >> 6, lane = tid & 63;
#pragma unroll
  for (int it = 0; it < 16; ++it) {
    int dl = it * 4 + w;
    tz[dl][lane] = z[((size_t)(b * D_ + d0 + dl)) * T_ + t0 + lane];  // coalesced along t
  }
  __syncthreads();
#pragma unroll
  for (int it = 0; it < 16; ++it) {
    int tl = it * 4 + w;
    size_t bt = (size_t)b * T_ + t0 + tl;
    float v = tz[lane][tl];                                // bank-spread (stride 65)
    encT[bt * D_ + d0 + lane] = v;                         // coalesced along d
    encTh[bt * D_ + d0 + lane] = (_Float16)v;
  }
}

// ---------------- prep: codebook norms (f64) + normalized f16 codebook ----------------
__global__ __launch_bounds__(256) void k_prep_cb(const float* __restrict__ cb,
                                                 _Float16* __restrict__ cbh,
                                                 double* __restrict__ nrm) {
  int k = blockIdx.x;
  int tid = threadIdx.x;
  float c0 = cb[(size_t)k * 512 + tid];
  float c1 = cb[(size_t)k * 512 + 256 + tid];
  double s = (double)c0 * c0 + (double)c1 * c1;
#pragma unroll
  for (int m = 1; m < 64; m <<= 1) s += __shfl_xor(s, m, 64);
  __shared__ double part[4];
  if ((tid & 63) == 0) part[tid >> 6] = s;
  __syncthreads();
  double tot = part[0] + part[1] + part[2] + part[3];
  double n = sqrt(tot);
  if (n < 1e-12) n = 1e-12;
  float inv = (float)(1.0 / n);
  cbh[(size_t)k * 512 + tid] = (_Float16)(c0 * inv);
  cbh[(size_t)k * 512 + 256 + tid] = (_Float16)(c1 * inv);
  if (tid == 0) nrm[k] = n;
}

// ---------------- top-2 insert (higher value wins; tie -> smaller index) ----------------
__device__ __forceinline__ void t2merge(float& v0, int& i0, float& v1, int& i1, float w, int j) {
  if (w > v0 || (w == v0 && j < i0)) {
    v1 = v0; i1 = i0; v0 = w; i0 = j;
  } else if (w > v1 || (w == v1 && j < i1)) {
    v1 = w; i1 = j;
  }
}

// ---------------- f16 MFMA GEMM (M=16384, N=8192, K=512), epilogue = per-row top2/64cols ----
// v5: K fully register-resident. Each wave owns 16 A-rows as 16 MFMA A-frags (64 VGPRs),
// streams cb rows global->VGPR->MFMA. NO LDS, NO global_load_lds, NO K-loop drains.
// Block = 4 waves x 16 rows = 64 rows; bh = bid&1 selects an N-half so each XCD
// (bid%8 fixed parity) streams ONE 4 MB cb half in order -> L2-resident.
// Fragment index mapping identical to the R2-R4 verified kernel.
__global__ __launch_bounds__(256, 2) void k_gemm_top2(const _Float16* __restrict__ A,
                                                      const _Float16* __restrict__ Bw,
                                                      float4* __restrict__ top2) {
  int bid = blockIdx.x;                 // 0..511
  int bh = bid & 1;                     // N-half: cols [bh*4096, bh*4096+4096)
  int bm = bid >> 1;                    // 0..255 row-tile of 64
  int tid = threadIdx.x;
  int w = tid >> 6, lane = tid & 63;
  int cgrp = lane & 15, rgrp = lane >> 4;     // MFMA fragment coords (verified mapping)
  int m0 = bm * 64 + w * 16;                  // wave's 16 output rows
  // A-strip: afrag[kk] covers rows m0..m0+15, k in [kk*32, kk*32+32)
  const _Float16* Arow = A + ((size_t)(m0 + cgrp)) * 512 + rgrp * 8;
  half8 afrag[16];
#pragma unroll
  for (int kk = 0; kk < 16; ++kk) afrag[kk] = *(const half8*)(Arow + kk * 32);

  int n0 = bh * 4096;
  for (int c64 = 0; c64 < 64; ++c64) {        // 64-col blocks within this half
    float v0[4], v1[4];
    int i0[4], i1[4];
#pragma unroll
    for (int r = 0; r < 4; ++r) {
      v0[r] = -3.4e38f; v1[r] = -3.4e38f;
      i0[r] = 0x7fffffff; i1[r] = 0x7fffffff;
    }
#pragma unroll
    for (int pr = 0; pr < 2; ++pr) {          // 2 x 32 cols
      int c0 = n0 + c64 * 64 + pr * 32 + cgrp;
      const _Float16* B0 = Bw + (size_t)c0 * 512 + rgrp * 8;
      const _Float16* B1 = B0 + 16 * 512;
      floatx4 p0 = floatx4{0.f, 0.f, 0.f, 0.f};
      floatx4 p1 = floatx4{0.f, 0.f, 0.f, 0.f};
#pragma unroll 8
      for (int kk = 0; kk < 16; ++kk) {       // two independent acc chains
        half8 b0 = *(const half8*)(B0 + kk * 32);
        half8 b1 = *(const half8*)(B1 + kk * 32);
        p0 = __builtin_amdgcn_mfma_f32_16x16x32_f16(afrag[kk], b0, p0, 0, 0, 0);
        p1 = __builtin_amdgcn_mfma_f32_16x16x32_f16(afrag[kk], b1, p1, 0, 0, 0);
      }
#pragma unroll
      for (int r = 0; r < 4; ++r) {
        t2merge(v0[r], i0[r], v1[r], i1[r], p0[r], c0);
        t2merge(v0[r], i0[r], v1[r], i1[r], p1[r], c0 + 16);
      }
    }
    // reduce across the 16 column-lanes (cgrp), then store
#pragma unroll
    for (int r = 0; r < 4; ++r) {
#pragma unroll
      for (int m = 1; m < 16; m <<= 1) {
        float ov0 = __shfl_xor(v0[r], m, 64);
        int oi0 = __shfl_xor(i0[r], m, 64);
        float ov1 = __shfl_xor(v1[r], m, 64);
        int oi1 = __shfl_xor(i1[r], m, 64);
        t2merge(v0[r], i0[r], v1[r], i1[r], ov0, oi0);
        t2merge(v0[r], i0[r], v1[r], i1[r], ov1, oi1);
      }
      if (cgrp == 0) {
        int grow = m0 + rgrp * 4 + r;
        float4 st;
        st.x = v0[r]; st.y = v1[r];
        st.z = __int_as_float(i0[r]); st.w = __int_as_float(i1[r]);
        top2[(size_t)grow * 128 + bh * 64 + c64] = st;
      }
    }
    __syncthreads();   // no shared data; keeps waves converged for L1 reuse of the B stream
  }
}

// ---------------- finalize: exact fp64 rescore of in-margin candidates, write indices ----
__global__ __launch_bounds__(64) void k_finalize(const float4* __restrict__ top2,
                                                 const float* __restrict__ encT,
                                                 const float* __restrict__ cb,
                                                 const double* __restrict__ nrm,
                                                 float* __restrict__ idxf) {
  int row = blockIdx.x;
  int lane = threadIdx.x;
  float4 e0 = top2[(size_t)row * 128 + lane * 2];
  float4 e1 = top2[(size_t)row * 128 + lane * 2 + 1];
  float mx = fmaxf(e0.x, e1.x);
#pragma unroll
  for (int m = 1; m < 64; m <<= 1) mx = fmaxf(mx, __shfl_xor(mx, m, 64));
  float thr = mx - MARGIN;
  float ev[8];
#pragma unroll
  for (int x = 0; x < 8; ++x) ev[x] = encT[(size_t)row * 512 + lane * 8 + x];
  double bs = -1e300;
  int bk = 0x7fffffff;
  float cv[4] = {e0.x, e0.y, e1.x, e1.y};
  int ci[4] = {__float_as_int(e0.z), __float_as_int(e0.w),
               __float_as_int(e1.z), __float_as_int(e1.w)};
#pragma unroll
  for (int j = 0; j < 4; ++j) {
    unsigned long long ball = __ballot(cv[j] >= thr);
    while (ball) {
      int src = __ffsll(ball) - 1;
      ball &= ball - 1;
      int k = __shfl(ci[j], src, 64);
      const float* crow = cb + (size_t)k * 512;
      double s = 0.0;
#pragma unroll
      for (int x = 0; x < 8; ++x) s += (double)ev[x] * (double)crow[lane * 8 + x];
#pragma unroll
      for (int m = 1; m < 64; m <<= 1) s += __shfl_xor(s, m, 64);
      double sc = s / nrm[k];
      if (sc > bs || (sc == bs && k < bk)) { bs = sc; bk = k; }
    }
  }
  if (lane == 0) idxf[row] = (float)bk;
}

// ---------------- gather: z_q / z_q_out = codebook[idx] (B,D,T-layout) * mask ----------------
__global__ __launch_bounds__(256) void k_gather(const float* __restrict__ cb,
                                                const float* __restrict__ idxf,
                                                const float* __restrict__ mask,
                                                float* __restrict__ zq,
                                                float* __restrict__ zqout) {
  int bid = blockIdx.x;
  int db = bid & 7, tb = (bid >> 3) & 31, b = bid >> 8;
  int d0 = db * 64, t0 = tb * 64;
  __shared__ float tile[64][65];
  __shared__ int kidx[64];
  __shared__ float mk[64];
  int tid = threadIdx.x, w = tid >> 6, lane = tid & 63;
  if (tid < 64) {
    kidx[tid] = (int)idxf[b * T_ + t0 + tid];
    mk[tid] = mask[b * T_ + t0 + tid];
  }
  __syncthreads();
#pragma unroll
  for (int it = 0; it < 16; ++it) {
    int tl = it * 4 + w;
    int k = kidx[tl];
    tile[lane][tl] = cb[(size_t)k * D_ + d0 + lane];       // coalesced cb row segment
  }
  __syncthreads();
#pragma unroll
  for (int it = 0; it < 16; ++it) {
    int dl = it * 4 + w;
    float v = tile[dl][lane] * mk[lane];
    size_t off = ((size_t)(b * D_ + d0 + dl)) * T_ + t0 + lane;  // coalesced along t
    zq[off] = v;
    zqout[off] = v;
  }
}

// ---------------- z_e = z (verbatim copy) ----------------
__global__ __launch_bounds__(256) void k_copy_ze(const float4* __restrict__ z4,
                                                 float4* __restrict__ o4) {
  size_t n4 = ZSZ / 4;
  for (size_t i = (size_t)blockIdx.x * 256 + threadIdx.x; i < n4; i += (size_t)gridDim.x * 256)
    o4[i] = z4[i];
}

extern "C" void kernel_launch(void* const* d_in, const int* in_sizes, int n_in,
                              void* d_out, int out_size, void* d_ws, size_t ws_size,
                              hipStream_t stream) {
  const float* z = (const float*)d_in[0];
  const float* mask = (const float*)d_in[1];
  const float* cb = (const float*)d_in[2];
  float* out = (float*)d_out;
  char* o = (char*)d_out;
  // ALL scratch lives inside d_out (100.7 MB); d_ws untouched (ws_size unknown/unsafe).
  //   seg0 [0,      SEGB): final z_q      | staging: encTh (16.8M) + cbh (8.4M) + nrm (64K)
  //   seg1 [SEGB,  2SEGB): final z_e      | staging: top2 (16384 x 128 float4 = 33.5M)
  //   seg2 [2SEGB, 3SEGB): final z_q_out  | staging: encT f32 (exactly 33.55M)
  //   seg3 [3SEGB, ...  ): final indices (float; finalize writes, gather reads back)
  // Write order: prep(seg0,seg2) -> gemm(seg1) -> finalize(seg3) -> gather(seg0,seg2) -> copy(seg1)
  _Float16* encTh = (_Float16*)(o);                       // 16,777,216 B
  _Float16* cbh   = (_Float16*)(o + 16777216);            //  8,388,608 B
  double*   nrm   = (double*)(o + 25165824);              //     65,536 B  (< SEGB total)
  float4*   top2  = (float4*)(o + SEGB);                  // 33,554,432 B
  float*    encT  = (float*)(o + 2 * SEGB);               // 33,554,432 B
  float*    idxf  = out + 3 * ZSZ;                        // 16384 floats (final output 3)
  float*    zq    = out;                                  // final output 0
  float*    ze    = out + ZSZ;                            // final output 1
  float*    zqout = out + 2 * ZSZ;                        // final output 2

  k_prep_z<<<2048, 256, 0, stream>>>(z, encT, encTh);
  k_prep_cb<<<8192, 256, 0, stream>>>(cb, cbh, nrm);
  k_gemm_top2<<<512, 256, 0, stream>>>(encTh, cbh, top2);
  k_finalize<<<16384, 64, 0, stream>>>(top2, encT, cb, nrm, idxf);
  k_gather<<<2048, 256, 0, stream>>>(cb, idxf, mask, zq, zqout);
  k_copy_ze<<<2048, 256, 0, stream>>>((const float4*)z, (float4*)ze);
}

// Round 6
// 2230.871 us; speedup vs baseline: 1.2644x; 1.2644x over previous
//
#include <hip/hip_runtime.h>
#include <hip/hip_fp16.h>

typedef _Float16 half8 __attribute__((ext_vector_type(8)));
typedef float floatx4 __attribute__((ext_vector_type(4)));

static constexpr int B_ = 8, D_ = 512, T_ = 2048, K_ = 8192;
static constexpr size_t ZSZ = (size_t)B_ * D_ * T_;   // 8388608 elems; one output segment
static constexpr size_t SEGB = ZSZ * 4;               // 33,554,432 bytes per segment
static constexpr float MARGIN = 0.02f;                // f16 screen err ~4e-3; 2x + slack

// ---------------- prep: transpose z (B,D,T) -> encT (BT,D) in f32 + f16 ----------------
__global__ __launch_bounds__(256) void k_prep_z(const float* __restrict__ z,
                                                float* __restrict__ encT,
                                                _Float16* __restrict__ encTh) {
  int bid = blockIdx.x;
  int db = bid & 7, tb = (bid >> 3) & 31, b = bid >> 8;   // 8 x 32 x 8 = 2048 blocks
  int d0 = db * 64, t0 = tb * 64;
  __shared__ float tz[64][65];
  int tid = threadIdx.x, w = tid >> 6, lane = tid & 63;
#pragma unroll
  for (int it = 0; it < 16; ++it) {
    int dl = it * 4 + w;
    tz[dl][lane] = z[((size_t)(b * D_ + d0 + dl)) * T_ + t0 + lane];  // coalesced along t
  }
  __syncthreads();
#pragma unroll
  for (int it = 0; it < 16; ++it) {
    int tl = it * 4 + w;
    size_t bt = (size_t)b * T_ + t0 + tl;
    float v = tz[lane][tl];                                // bank-spread (stride 65)
    encT[bt * D_ + d0 + lane] = v;                         // coalesced along d
    encTh[bt * D_ + d0 + lane] = (_Float16)v;
  }
}

// ---------------- prep: codebook norms (f64) + normalized f16 codebook ----------------
__global__ __launch_bounds__(256) void k_prep_cb(const float* __restrict__ cb,
                                                 _Float16* __restrict__ cbh,
                                                 double* __restrict__ nrm) {
  int k = blockIdx.x;
  int tid = threadIdx.x;
  float c0 = cb[(size_t)k * 512 + tid];
  float c1 = cb[(size_t)k * 512 + 256 + tid];
  double s = (double)c0 * c0 + (double)c1 * c1;
#pragma unroll
  for (int m = 1; m < 64; m <<= 1) s += __shfl_xor(s, m, 64);
  __shared__ double part[4];
  if ((tid & 63) == 0) part[tid >> 6] = s;
  __syncthreads();
  double tot = part[0] + part[1] + part[2] + part[3];
  double n = sqrt(tot);
  if (n < 1e-12) n = 1e-12;
  float inv = (float)(1.0 / n);
  cbh[(size_t)k * 512 + tid] = (_Float16)(c0 * inv);
  cbh[(size_t)k * 512 + 256 + tid] = (_Float16)(c1 * inv);
  if (tid == 0) nrm[k] = n;
}

// ---------------- top-2 insert (higher value wins; tie -> smaller index) ----------------
__device__ __forceinline__ void t2merge(float& v0, int& i0, float& v1, int& i1, float w, int j) {
  if (w > v0 || (w == v0 && j < i0)) {
    v1 = v0; i1 = i0; v0 = w; i0 = j;
  } else if (w > v1 || (w == v1 && j < i1)) {
    v1 = w; i1 = j;
  }
}

// ---------------- f16 MFMA GEMM (M=16384, N=8192, K=512), epilogue = per-row top2/64cols ----
// v6 = v5 structure with STATIC register indexing everywhere (rule #20: R5's
// `#pragma unroll 8` made afrag[kk] runtime-indexed -> scratch; VGPR=32, 1.6 GB
// scratch writes). kk-loop = 4 statically unrolled groups of 4, b-staging static.
__global__ __launch_bounds__(256, 2) void k_gemm_top2(const _Float16* __restrict__ A,
                                                      const _Float16* __restrict__ Bw,
                                                      float4* __restrict__ top2) {
  int bid = blockIdx.x;                 // 0..511
  int bh = bid & 1;                     // N-half: cols [bh*4096, +4096); XCD=bid%8 -> fixed
  int bm = bid >> 1;                    // 0..255 row-tile of 64
  int tid = threadIdx.x;
  int w = tid >> 6, lane = tid & 63;
  int cgrp = lane & 15, rgrp = lane >> 4;     // MFMA fragment coords (verified mapping)
  int m0 = bm * 64 + w * 16;                  // wave's 16 output rows
  const _Float16* Arow = A + ((size_t)(m0 + cgrp)) * 512 + rgrp * 8;
  half8 afrag[16];
#pragma unroll
  for (int kk = 0; kk < 16; ++kk) afrag[kk] = *(const half8*)(Arow + kk * 32);

  int n0 = bh * 4096;
  for (int c64 = 0; c64 < 64; ++c64) {        // 64-col blocks within this half
    float v0[4], v1[4];
    int i0[4], i1[4];
#pragma unroll
    for (int r = 0; r < 4; ++r) {
      v0[r] = -3.4e38f; v1[r] = -3.4e38f;
      i0[r] = 0x7fffffff; i1[r] = 0x7fffffff;
    }
#pragma unroll
    for (int pr = 0; pr < 2; ++pr) {          // 2 x 32 cols
      int c0 = n0 + c64 * 64 + pr * 32 + cgrp;
      const _Float16* B0 = Bw + (size_t)c0 * 512 + rgrp * 8;
      const _Float16* B1 = B0 + 16 * 512;
      floatx4 p0 = floatx4{0.f, 0.f, 0.f, 0.f};
      floatx4 p1 = floatx4{0.f, 0.f, 0.f, 0.f};
#pragma unroll
      for (int kg = 0; kg < 4; ++kg) {        // 4 static groups of 4 -> all indices const
        half8 b0s[4], b1s[4];
#pragma unroll
        for (int j = 0; j < 4; ++j) {
          b0s[j] = *(const half8*)(B0 + (kg * 4 + j) * 32);
          b1s[j] = *(const half8*)(B1 + (kg * 4 + j) * 32);
        }
#pragma unroll
        for (int j = 0; j < 4; ++j) {
          p0 = __builtin_amdgcn_mfma_f32_16x16x32_f16(afrag[kg * 4 + j], b0s[j], p0, 0, 0, 0);
          p1 = __builtin_amdgcn_mfma_f32_16x16x32_f16(afrag[kg * 4 + j], b1s[j], p1, 0, 0, 0);
        }
      }
#pragma unroll
      for (int r = 0; r < 4; ++r) {
        t2merge(v0[r], i0[r], v1[r], i1[r], p0[r], c0);
        t2merge(v0[r], i0[r], v1[r], i1[r], p1[r], c0 + 16);
      }
    }
    // reduce across the 16 column-lanes (cgrp), then store
#pragma unroll
    for (int r = 0; r < 4; ++r) {
#pragma unroll
      for (int m = 1; m < 16; m <<= 1) {
        float ov0 = __shfl_xor(v0[r], m, 64);
        int oi0 = __shfl_xor(i0[r], m, 64);
        float ov1 = __shfl_xor(v1[r], m, 64);
        int oi1 = __shfl_xor(i1[r], m, 64);
        t2merge(v0[r], i0[r], v1[r], i1[r], ov0, oi0);
        t2merge(v0[r], i0[r], v1[r], i1[r], ov1, oi1);
      }
      if (cgrp == 0) {
        int grow = m0 + rgrp * 4 + r;
        float4 st;
        st.x = v0[r]; st.y = v1[r];
        st.z = __int_as_float(i0[r]); st.w = __int_as_float(i1[r]);
        top2[(size_t)grow * 128 + bh * 64 + c64] = st;
      }
    }
    __syncthreads();   // no shared data; keeps waves converged for L1 reuse of the B stream
  }
}

// ---------------- finalize: exact fp64 rescore of in-margin candidates, write indices ----
__global__ __launch_bounds__(64) void k_finalize(const float4* __restrict__ top2,
                                                 const float* __restrict__ encT,
                                                 const float* __restrict__ cb,
                                                 const double* __restrict__ nrm,
                                                 float* __restrict__ idxf) {
  int row = blockIdx.x;
  int lane = threadIdx.x;
  float4 e0 = top2[(size_t)row * 128 + lane * 2];
  float4 e1 = top2[(size_t)row * 128 + lane * 2 + 1];
  float mx = fmaxf(e0.x, e1.x);
#pragma unroll
  for (int m = 1; m < 64; m <<= 1) mx = fmaxf(mx, __shfl_xor(mx, m, 64));
  float thr = mx - MARGIN;
  float ev[8];
#pragma unroll
  for (int x = 0; x < 8; ++x) ev[x] = encT[(size_t)row * 512 + lane * 8 + x];
  double bs = -1e300;
  int bk = 0x7fffffff;
  float cv[4] = {e0.x, e0.y, e1.x, e1.y};
  int ci[4] = {__float_as_int(e0.z), __float_as_int(e0.w),
               __float_as_int(e1.z), __float_as_int(e1.w)};
#pragma unroll
  for (int j = 0; j < 4; ++j) {
    unsigned long long ball = __ballot(cv[j] >= thr);
    while (ball) {
      int src = __ffsll(ball) - 1;
      ball &= ball - 1;
      int k = __shfl(ci[j], src, 64);
      const float* crow = cb + (size_t)k * 512;
      double s = 0.0;
#pragma unroll
      for (int x = 0; x < 8; ++x) s += (double)ev[x] * (double)crow[lane * 8 + x];
#pragma unroll
      for (int m = 1; m < 64; m <<= 1) s += __shfl_xor(s, m, 64);
      double sc = s / nrm[k];
      if (sc > bs || (sc == bs && k < bk)) { bs = sc; bk = k; }
    }
  }
  if (lane == 0) idxf[row] = (float)bk;
}

// ---------------- gather: z_q / z_q_out = codebook[idx] (B,D,T-layout) * mask ----------------
__global__ __launch_bounds__(256) void k_gather(const float* __restrict__ cb,
                                                const float* __restrict__ idxf,
                                                const float* __restrict__ mask,
                                                float* __restrict__ zq,
                                                float* __restrict__ zqout) {
  int bid = blockIdx.x;
  int db = bid & 7, tb = (bid >> 3) & 31, b = bid >> 8;
  int d0 = db * 64, t0 = tb * 64;
  __shared__ float tile[64][65];
  __shared__ int kidx[64];
  __shared__ float mk[64];
  int tid = threadIdx.x, w = tid >> 6, lane = tid & 63;
  if (tid < 64) {
    kidx[tid] = (int)idxf[b * T_ + t0 + tid];
    mk[tid] = mask[b * T_ + t0 + tid];
  }
  __syncthreads();
#pragma unroll
  for (int it = 0; it < 16; ++it) {
    int tl = it * 4 + w;
    int k = kidx[tl];
    tile[lane][tl] = cb[(size_t)k * D_ + d0 + lane];       // coalesced cb row segment
  }
  __syncthreads();
#pragma unroll
  for (int it = 0; it < 16; ++it) {
    int dl = it * 4 + w;
    float v = tile[dl][lane] * mk[lane];
    size_t off = ((size_t)(b * D_ + d0 + dl)) * T_ + t0 + lane;  // coalesced along t
    zq[off] = v;
    zqout[off] = v;
  }
}

// ---------------- z_e = z (verbatim copy) ----------------
__global__ __launch_bounds__(256) void k_copy_ze(const float4* __restrict__ z4,
                                                 float4* __restrict__ o4) {
  size_t n4 = ZSZ / 4;
  for (size_t i = (size_t)blockIdx.x * 256 + threadIdx.x; i < n4; i += (size_t)gridDim.x * 256)
    o4[i] = z4[i];
}

extern "C" void kernel_launch(void* const* d_in, const int* in_sizes, int n_in,
                              void* d_out, int out_size, void* d_ws, size_t ws_size,
                              hipStream_t stream) {
  const float* z = (const float*)d_in[0];
  const float* mask = (const float*)d_in[1];
  const float* cb = (const float*)d_in[2];
  float* out = (float*)d_out;
  char* o = (char*)d_out;
  // ALL scratch lives inside d_out (100.7 MB); d_ws untouched (ws_size unknown/unsafe).
  //   seg0 [0,      SEGB): final z_q      | staging: encTh (16.8M) + cbh (8.4M) + nrm (64K)
  //   seg1 [SEGB,  2SEGB): final z_e      | staging: top2 (16384 x 128 float4 = 33.5M)
  //   seg2 [2SEGB, 3SEGB): final z_q_out  | staging: encT f32 (exactly 33.55M)
  //   seg3 [3SEGB, ...  ): final indices (float; finalize writes, gather reads back)
  // Write order: prep(seg0,seg2) -> gemm(seg1) -> finalize(seg3) -> gather(seg0,seg2) -> copy(seg1)
  _Float16* encTh = (_Float16*)(o);                       // 16,777,216 B
  _Float16* cbh   = (_Float16*)(o + 16777216);            //  8,388,608 B
  double*   nrm   = (double*)(o + 25165824);              //     65,536 B  (< SEGB total)
  float4*   top2  = (float4*)(o + SEGB);                  // 33,554,432 B
  float*    encT  = (float*)(o + 2 * SEGB);               // 33,554,432 B
  float*    idxf  = out + 3 * ZSZ;                        // 16384 floats (final output 3)
  float*    zq    = out;                                  // final output 0
  float*    ze    = out + ZSZ;                            // final output 1
  float*    zqout = out + 2 * ZSZ;                        // final output 2

  k_prep_z<<<2048, 256, 0, stream>>>(z, encT, encTh);
  k_prep_cb<<<8192, 256, 0, stream>>>(cb, cbh, nrm);
  k_gemm_top2<<<512, 256, 0, stream>>>(encTh, cbh, top2);
  k_finalize<<<16384, 64, 0, stream>>>(top2, encT, cb, nrm, idxf);
  k_gather<<<2048, 256, 0, stream>>>(cb, idxf, mask, zq, zqout);
  k_copy_ze<<<2048, 256, 0, stream>>>((const float4*)z, (float4*)ze);
}

// Round 7
// 2224.235 us; speedup vs baseline: 1.2682x; 1.0030x over previous
//
#include <hip/hip_runtime.h>
#include <hip/hip_fp16.h>

typedef _Float16 half8 __attribute__((ext_vector_type(8)));
typedef float floatx4 __attribute__((ext_vector_type(4)));

static constexpr int B_ = 8, D_ = 512, T_ = 2048, K_ = 8192;
static constexpr size_t ZSZ = (size_t)B_ * D_ * T_;   // 8388608 elems; one output segment
static constexpr size_t SEGB = ZSZ * 4;               // 33,554,432 bytes per segment
static constexpr float MARGIN = 0.02f;                // f16 screen err ~4e-3; 2x + slack

// ---------------- prep: transpose z (B,D,T) -> encT (BT,D) in f32 + f16 ----------------
__global__ __launch_bounds__(256) void k_prep_z(const float* __restrict__ z,
                                                float* __restrict__ encT,
                                                _Float16* __restrict__ encTh) {
  int bid = blockIdx.x;
  int db = bid & 7, tb = (bid >> 3) & 31, b = bid >> 8;   // 8 x 32 x 8 = 2048 blocks
  int d0 = db * 64, t0 = tb * 64;
  __shared__ float tz[64][65];
  int tid = threadIdx.x, w = tid >> 6, lane = tid & 63;
#pragma unroll
  for (int it = 0; it < 16; ++it) {
    int dl = it * 4 + w;
    tz[dl][lane] = z[((size_t)(b * D_ + d0 + dl)) * T_ + t0 + lane];  // coalesced along t
  }
  __syncthreads();
#pragma unroll
  for (int it = 0; it < 16; ++it) {
    int tl = it * 4 + w;
    size_t bt = (size_t)b * T_ + t0 + tl;
    float v = tz[lane][tl];                                // bank-spread (stride 65)
    encT[bt * D_ + d0 + lane] = v;                         // coalesced along d
    encTh[bt * D_ + d0 + lane] = (_Float16)v;
  }
}

// ---------------- prep: codebook norms (f64) + normalized f16 codebook ----------------
__global__ __launch_bounds__(256) void k_prep_cb(const float* __restrict__ cb,
                                                 _Float16* __restrict__ cbh,
                                                 double* __restrict__ nrm) {
  int k = blockIdx.x;
  int tid = threadIdx.x;
  float c0 = cb[(size_t)k * 512 + tid];
  float c1 = cb[(size_t)k * 512 + 256 + tid];
  double s = (double)c0 * c0 + (double)c1 * c1;
#pragma unroll
  for (int m = 1; m < 64; m <<= 1) s += __shfl_xor(s, m, 64);
  __shared__ double part[4];
  if ((tid & 63) == 0) part[tid >> 6] = s;
  __syncthreads();
  double tot = part[0] + part[1] + part[2] + part[3];
  double n = sqrt(tot);
  if (n < 1e-12) n = 1e-12;
  float inv = (float)(1.0 / n);
  cbh[(size_t)k * 512 + tid] = (_Float16)(c0 * inv);
  cbh[(size_t)k * 512 + 256 + tid] = (_Float16)(c1 * inv);
  if (tid == 0) nrm[k] = n;
}

// ---------------- top-2 insert (higher value wins; tie -> smaller index) ----------------
__device__ __forceinline__ void t2merge(float& v0, int& i0, float& v1, int& i1, float w, int j) {
  if (w > v0 || (w == v0 && j < i0)) {
    v1 = v0; i1 = i0; v0 = w; i0 = j;
  } else if (w > v1 || (w == v1 && j < i1)) {
    v1 = w; i1 = j;
  }
}

// ---------------- f16 MFMA GEMM (M=16384, N=8192, K=512), epilogue = per-row top2/64cols ----
// v7 = v6 with the A-strip in 16 INDIVIDUALLY-NAMED half8 values (no array object can
// reach the stack; SROA keeps pure SSA -> VGPRs). R6 evidence: VGPR=56 + 145 MB scratch
// writes showed the afrag ARRAY was lowered to scratch even with static indices.
#define MFMA16(a, b, p) p = __builtin_amdgcn_mfma_f32_16x16x32_f16((a), (b), (p), 0, 0, 0)
#define KGROUP(A0, A1, A2, A3, OFF) do {                        \
    half8 q00 = *(const half8*)(B0 + (OFF + 0) * 32);           \
    half8 q01 = *(const half8*)(B0 + (OFF + 1) * 32);           \
    half8 q02 = *(const half8*)(B0 + (OFF + 2) * 32);           \
    half8 q03 = *(const half8*)(B0 + (OFF + 3) * 32);           \
    half8 q10 = *(const half8*)(B1 + (OFF + 0) * 32);           \
    half8 q11 = *(const half8*)(B1 + (OFF + 1) * 32);           \
    half8 q12 = *(const half8*)(B1 + (OFF + 2) * 32);           \
    half8 q13 = *(const half8*)(B1 + (OFF + 3) * 32);           \
    MFMA16(A0, q00, p0); MFMA16(A0, q10, p1);                   \
    MFMA16(A1, q01, p0); MFMA16(A1, q11, p1);                   \
    MFMA16(A2, q02, p0); MFMA16(A2, q12, p1);                   \
    MFMA16(A3, q03, p0); MFMA16(A3, q13, p1);                   \
  } while (0)

__global__ __launch_bounds__(256, 2) void k_gemm_top2(const _Float16* __restrict__ A,
                                                      const _Float16* __restrict__ Bw,
                                                      float4* __restrict__ top2) {
  int bid = blockIdx.x;                 // 0..511
  int bh = bid & 1;                     // N-half: cols [bh*4096, +4096); XCD=bid%8 -> fixed
  int bm = bid >> 1;                    // 0..255 row-tile of 64
  int tid = threadIdx.x;
  int w = tid >> 6, lane = tid & 63;
  int cgrp = lane & 15, rgrp = lane >> 4;     // MFMA fragment coords (verified mapping)
  int m0 = bm * 64 + w * 16;                  // wave's 16 output rows
  const _Float16* Arow = A + ((size_t)(m0 + cgrp)) * 512 + rgrp * 8;
  half8 a00 = *(const half8*)(Arow + 0 * 32);
  half8 a01 = *(const half8*)(Arow + 1 * 32);
  half8 a02 = *(const half8*)(Arow + 2 * 32);
  half8 a03 = *(const half8*)(Arow + 3 * 32);
  half8 a04 = *(const half8*)(Arow + 4 * 32);
  half8 a05 = *(const half8*)(Arow + 5 * 32);
  half8 a06 = *(const half8*)(Arow + 6 * 32);
  half8 a07 = *(const half8*)(Arow + 7 * 32);
  half8 a08 = *(const half8*)(Arow + 8 * 32);
  half8 a09 = *(const half8*)(Arow + 9 * 32);
  half8 a10 = *(const half8*)(Arow + 10 * 32);
  half8 a11 = *(const half8*)(Arow + 11 * 32);
  half8 a12 = *(const half8*)(Arow + 12 * 32);
  half8 a13 = *(const half8*)(Arow + 13 * 32);
  half8 a14 = *(const half8*)(Arow + 14 * 32);
  half8 a15 = *(const half8*)(Arow + 15 * 32);

  int n0 = bh * 4096;
  for (int c64 = 0; c64 < 64; ++c64) {        // 64-col blocks within this half
    float v0[4], v1[4];
    int i0[4], i1[4];
#pragma unroll
    for (int r = 0; r < 4; ++r) {
      v0[r] = -3.4e38f; v1[r] = -3.4e38f;
      i0[r] = 0x7fffffff; i1[r] = 0x7fffffff;
    }
#pragma unroll
    for (int pr = 0; pr < 2; ++pr) {          // 2 x 32 cols
      int c0 = n0 + c64 * 64 + pr * 32 + cgrp;
      const _Float16* B0 = Bw + (size_t)c0 * 512 + rgrp * 8;
      const _Float16* B1 = B0 + 16 * 512;
      floatx4 p0 = floatx4{0.f, 0.f, 0.f, 0.f};
      floatx4 p1 = floatx4{0.f, 0.f, 0.f, 0.f};
      KGROUP(a00, a01, a02, a03, 0);
      KGROUP(a04, a05, a06, a07, 4);
      KGROUP(a08, a09, a10, a11, 8);
      KGROUP(a12, a13, a14, a15, 12);
#pragma unroll
      for (int r = 0; r < 4; ++r) {
        t2merge(v0[r], i0[r], v1[r], i1[r], p0[r], c0);
        t2merge(v0[r], i0[r], v1[r], i1[r], p1[r], c0 + 16);
      }
    }
    // reduce across the 16 column-lanes (cgrp), then store
#pragma unroll
    for (int r = 0; r < 4; ++r) {
#pragma unroll
      for (int m = 1; m < 16; m <<= 1) {
        float ov0 = __shfl_xor(v0[r], m, 64);
        int oi0 = __shfl_xor(i0[r], m, 64);
        float ov1 = __shfl_xor(v1[r], m, 64);
        int oi1 = __shfl_xor(i1[r], m, 64);
        t2merge(v0[r], i0[r], v1[r], i1[r], ov0, oi0);
        t2merge(v0[r], i0[r], v1[r], i1[r], ov1, oi1);
      }
      if (cgrp == 0) {
        int grow = m0 + rgrp * 4 + r;
        float4 st;
        st.x = v0[r]; st.y = v1[r];
        st.z = __int_as_float(i0[r]); st.w = __int_as_float(i1[r]);
        top2[(size_t)grow * 128 + bh * 64 + c64] = st;
      }
    }
    __syncthreads();   // no shared data; keeps waves converged for L1/L2 reuse of the B stream
  }
}

// ---------------- finalize: exact fp64 rescore of in-margin candidates, write indices ----
__global__ __launch_bounds__(64) void k_finalize(const float4* __restrict__ top2,
                                                 const float* __restrict__ encT,
                                                 const float* __restrict__ cb,
                                                 const double* __restrict__ nrm,
                                                 float* __restrict__ idxf) {
  int row = blockIdx.x;
  int lane = threadIdx.x;
  float4 e0 = top2[(size_t)row * 128 + lane * 2];
  float4 e1 = top2[(size_t)row * 128 + lane * 2 + 1];
  float mx = fmaxf(e0.x, e1.x);
#pragma unroll
  for (int m = 1; m < 64; m <<= 1) mx = fmaxf(mx, __shfl_xor(mx, m, 64));
  float thr = mx - MARGIN;
  float ev[8];
#pragma unroll
  for (int x = 0; x < 8; ++x) ev[x] = encT[(size_t)row * 512 + lane * 8 + x];
  double bs = -1e300;
  int bk = 0x7fffffff;
  float cv[4] = {e0.x, e0.y, e1.x, e1.y};
  int ci[4] = {__float_as_int(e0.z), __float_as_int(e0.w),
               __float_as_int(e1.z), __float_as_int(e1.w)};
#pragma unroll
  for (int j = 0; j < 4; ++j) {
    unsigned long long ball = __ballot(cv[j] >= thr);
    while (ball) {
      int src = __ffsll(ball) - 1;
      ball &= ball - 1;
      int k = __shfl(ci[j], src, 64);
      const float* crow = cb + (size_t)k * 512;
      double s = 0.0;
#pragma unroll
      for (int x = 0; x < 8; ++x) s += (double)ev[x] * (double)crow[lane * 8 + x];
#pragma unroll
      for (int m = 1; m < 64; m <<= 1) s += __shfl_xor(s, m, 64);
      double sc = s / nrm[k];
      if (sc > bs || (sc == bs && k < bk)) { bs = sc; bk = k; }
    }
  }
  if (lane == 0) idxf[row] = (float)bk;
}

// ---------------- gather: z_q / z_q_out = codebook[idx] (B,D,T-layout) * mask ----------------
__global__ __launch_bounds__(256) void k_gather(const float* __restrict__ cb,
                                                const float* __restrict__ idxf,
                                                const float* __restrict__ mask,
                                                float* __restrict__ zq,
                                                float* __restrict__ zqout) {
  int bid = blockIdx.x;
  int db = bid & 7, tb = (bid >> 3) & 31, b = bid >> 8;
  int d0 = db * 64, t0 = tb * 64;
  __shared__ float tile[64][65];
  __shared__ int kidx[64];
  __shared__ float mk[64];
  int tid = threadIdx.x, w = tid >> 6, lane = tid & 63;
  if (tid < 64) {
    kidx[tid] = (int)idxf[b * T_ + t0 + tid];
    mk[tid] = mask[b * T_ + t0 + tid];
  }
  __syncthreads();
#pragma unroll
  for (int it = 0; it < 16; ++it) {
    int tl = it * 4 + w;
    int k = kidx[tl];
    tile[lane][tl] = cb[(size_t)k * D_ + d0 + lane];       // coalesced cb row segment
  }
  __syncthreads();
#pragma unroll
  for (int it = 0; it < 16; ++it) {
    int dl = it * 4 + w;
    float v = tile[dl][lane] * mk[lane];
    size_t off = ((size_t)(b * D_ + d0 + dl)) * T_ + t0 + lane;  // coalesced along t
    zq[off] = v;
    zqout[off] = v;
  }
}

// ---------------- z_e = z (verbatim copy) ----------------
__global__ __launch_bounds__(256) void k_copy_ze(const float4* __restrict__ z4,
                                                 float4* __restrict__ o4) {
  size_t n4 = ZSZ / 4;
  for (size_t i = (size_t)blockIdx.x * 256 + threadIdx.x; i < n4; i += (size_t)gridDim.x * 256)
    o4[i] = z4[i];
}

extern "C" void kernel_launch(void* const* d_in, const int* in_sizes, int n_in,
                              void* d_out, int out_size, void* d_ws, size_t ws_size,
                              hipStream_t stream) {
  const float* z = (const float*)d_in[0];
  const float* mask = (const float*)d_in[1];
  const float* cb = (const float*)d_in[2];
  float* out = (float*)d_out;
  char* o = (char*)d_out;
  // ALL scratch lives inside d_out (100.7 MB); d_ws untouched (ws_size unknown/unsafe).
  //   seg0 [0,      SEGB): final z_q      | staging: encTh (16.8M) + cbh (8.4M) + nrm (64K)
  //   seg1 [SEGB,  2SEGB): final z_e      | staging: top2 (16384 x 128 float4 = 33.5M)
  //   seg2 [2SEGB, 3SEGB): final z_q_out  | staging: encT f32 (exactly 33.55M)
  //   seg3 [3SEGB, ...  ): final indices (float; finalize writes, gather reads back)
  // Write order: prep(seg0,seg2) -> gemm(seg1) -> finalize(seg3) -> gather(seg0,seg2) -> copy(seg1)
  _Float16* encTh = (_Float16*)(o);                       // 16,777,216 B
  _Float16* cbh   = (_Float16*)(o + 16777216);            //  8,388,608 B
  double*   nrm   = (double*)(o + 25165824);              //     65,536 B  (< SEGB total)
  float4*   top2  = (float4*)(o + SEGB);                  // 33,554,432 B
  float*    encT  = (float*)(o + 2 * SEGB);               // 33,554,432 B
  float*    idxf  = out + 3 * ZSZ;                        // 16384 floats (final output 3)
  float*    zq    = out;                                  // final output 0
  float*    ze    = out + ZSZ;                            // final output 1
  float*    zqout = out + 2 * ZSZ;                        // final output 2

  k_prep_z<<<2048, 256, 0, stream>>>(z, encT, encTh);
  k_prep_cb<<<8192, 256, 0, stream>>>(cb, cbh, nrm);
  k_gemm_top2<<<512, 256, 0, stream>>>(encTh, cbh, top2);
  k_finalize<<<16384, 64, 0, stream>>>(top2, encT, cb, nrm, idxf);
  k_gather<<<2048, 256, 0, stream>>>(cb, idxf, mask, zq, zqout);
  k_copy_ze<<<2048, 256, 0, stream>>>((const float4*)z, (float4*)ze);
}

// Round 8
// 1300.731 us; speedup vs baseline: 2.1686x; 1.7100x over previous
//
#include <hip/hip_runtime.h>
#include <hip/hip_fp16.h>

typedef _Float16 half8 __attribute__((ext_vector_type(8)));
typedef float floatx4 __attribute__((ext_vector_type(4)));

static constexpr int B_ = 8, D_ = 512, T_ = 2048, K_ = 8192;
static constexpr size_t ZSZ = (size_t)B_ * D_ * T_;   // 8388608 elems; one output segment
static constexpr size_t SEGB = ZSZ * 4;               // 33,554,432 bytes per segment
static constexpr float MARGIN = 0.02f;                // f16 screen err; margin + fp64 rescore

// ---------------- prep: transpose z (B,D,T) -> encT (BT,D) in f32 + f16 ----------------
__global__ __launch_bounds__(256) void k_prep_z(const float* __restrict__ z,
                                                float* __restrict__ encT,
                                                _Float16* __restrict__ encTh) {
  int bid = blockIdx.x;
  int db = bid & 7, tb = (bid >> 3) & 31, b = bid >> 8;   // 8 x 32 x 8 = 2048 blocks
  int d0 = db * 64, t0 = tb * 64;
  __shared__ float tz[64][65];
  int tid = threadIdx.x, w = tid >> 6, lane = tid & 63;
#pragma unroll
  for (int it = 0; it < 16; ++it) {
    int dl = it * 4 + w;
    tz[dl][lane] = z[((size_t)(b * D_ + d0 + dl)) * T_ + t0 + lane];  // coalesced along t
  }
  __syncthreads();
#pragma unroll
  for (int it = 0; it < 16; ++it) {
    int tl = it * 4 + w;
    size_t bt = (size_t)b * T_ + t0 + tl;
    float v = tz[lane][tl];                                // bank-spread (stride 65)
    encT[bt * D_ + d0 + lane] = v;                         // coalesced along d
    encTh[bt * D_ + d0 + lane] = (_Float16)v;
  }
}

// ---------------- prep: codebook norms (f64) + normalized f16 codebook ----------------
__global__ __launch_bounds__(256) void k_prep_cb(const float* __restrict__ cb,
                                                 _Float16* __restrict__ cbh,
                                                 double* __restrict__ nrm) {
  int k = blockIdx.x;
  int tid = threadIdx.x;
  float c0 = cb[(size_t)k * 512 + tid];
  float c1 = cb[(size_t)k * 512 + 256 + tid];
  double s = (double)c0 * c0 + (double)c1 * c1;
#pragma unroll
  for (int m = 1; m < 64; m <<= 1) s += __shfl_xor(s, m, 64);
  __shared__ double part[4];
  if ((tid & 63) == 0) part[tid >> 6] = s;
  __syncthreads();
  double tot = part[0] + part[1] + part[2] + part[3];
  double n = sqrt(tot);
  if (n < 1e-12) n = 1e-12;
  float inv = (float)(1.0 / n);
  cbh[(size_t)k * 512 + tid] = (_Float16)(c0 * inv);
  cbh[(size_t)k * 512 + 256 + tid] = (_Float16)(c1 * inv);
  if (tid == 0) nrm[k] = n;
}

// ---------------- top-2 insert (higher value wins; tie -> smaller index) ----------------
__device__ __forceinline__ void t2merge(float& v0, int& i0, float& v1, int& i1, float w, int j) {
  if (w > v0 || (w == v0 && j < i0)) {
    v1 = v0; i1 = i0; v0 = w; i0 = j;
  } else if (w > v1 || (w == v1 && j < i1)) {
    v1 = w; i1 = j;
  }
}

// ---------------- f16 MFMA GEMM (M=16384, N=8192, K=512), epilogue = per-row top2/512cols ----
// v8: issue-economy design. Per wave: 16 rows A in 16 named half8 PINNED to arch VGPRs
// (asm "+v" — R6/R7 evidence: compiler AGPR-split left 56 arch VGPRs and emitted serial
// load->wait->mfma chains, 4096 x ~500cyc = the whole 2250us). Per 16-col group: 16 named
// B loads issued as one cluster (16-deep vmcnt), one wait, 16 MFMA on two 8-deep chains.
// No LDS / no global_load_lds / no vmcnt(0) drains. Grid: 256 row-tiles x 8 col-eighths;
// col-eighth == bid&7 == XCD -> 1MB B-slice L2-resident per XCD. Raw s_barrier (no wait)
// every 4 groups keeps the 4 waves converged so B-loads hit L1 3/4 of the time.
#define MFMA16(a, b, p) p = __builtin_amdgcn_mfma_f32_16x16x32_f16((a), (b), (p), 0, 0, 0)

__global__ __launch_bounds__(256, 2) void k_gemm_top2(const _Float16* __restrict__ A,
                                                      const _Float16* __restrict__ Bw,
                                                      float4* __restrict__ top2) {
  int bid = blockIdx.x;                 // 0..2047
  int ne = bid & 7;                     // col-eighth = XCD id; cols [ne*1024, +1024)
  int bm = bid >> 3;                    // 0..255 row-tile of 64
  int tid = threadIdx.x;
  int w = tid >> 6, lane = tid & 63;
  int cgrp = lane & 15, rgrp = lane >> 4;     // MFMA fragment coords (verified mapping)
  int m0 = bm * 64 + w * 16;                  // wave's 16 output rows

  const _Float16* Arow = A + ((size_t)(m0 + cgrp)) * 512 + rgrp * 8;
  half8 a00 = *(const half8*)(Arow + 0 * 32);
  half8 a01 = *(const half8*)(Arow + 1 * 32);
  half8 a02 = *(const half8*)(Arow + 2 * 32);
  half8 a03 = *(const half8*)(Arow + 3 * 32);
  half8 a04 = *(const half8*)(Arow + 4 * 32);
  half8 a05 = *(const half8*)(Arow + 5 * 32);
  half8 a06 = *(const half8*)(Arow + 6 * 32);
  half8 a07 = *(const half8*)(Arow + 7 * 32);
  half8 a08 = *(const half8*)(Arow + 8 * 32);
  half8 a09 = *(const half8*)(Arow + 9 * 32);
  half8 a10 = *(const half8*)(Arow + 10 * 32);
  half8 a11 = *(const half8*)(Arow + 11 * 32);
  half8 a12 = *(const half8*)(Arow + 12 * 32);
  half8 a13 = *(const half8*)(Arow + 13 * 32);
  half8 a14 = *(const half8*)(Arow + 14 * 32);
  half8 a15 = *(const half8*)(Arow + 15 * 32);
  // Pin the A-strip to arch VGPRs (defeat AGPR-split / keep live without stack).
  asm volatile("" : "+v"(a00), "+v"(a01), "+v"(a02), "+v"(a03),
                    "+v"(a04), "+v"(a05), "+v"(a06), "+v"(a07),
                    "+v"(a08), "+v"(a09), "+v"(a10), "+v"(a11),
                    "+v"(a12), "+v"(a13), "+v"(a14), "+v"(a15));

  int n0 = ne * 1024;
  float v0[4], v1[4];
  int i0[4], i1[4];
#pragma unroll
  for (int r = 0; r < 4; ++r) {
    v0[r] = -3.4e38f; v1[r] = -3.4e38f;
    i0[r] = 0x7fffffff; i1[r] = 0x7fffffff;
  }

  for (int g = 0; g < 64; ++g) {              // 64 groups of 16 cols
    int c0 = n0 + g * 16 + cgrp;              // this lane's column
    const _Float16* Bp = Bw + (size_t)c0 * 512 + rgrp * 8;
    // 16 independent named loads -> compiler clusters them, 16-deep vmcnt
    half8 q00 = *(const half8*)(Bp + 0 * 32);
    half8 q01 = *(const half8*)(Bp + 1 * 32);
    half8 q02 = *(const half8*)(Bp + 2 * 32);
    half8 q03 = *(const half8*)(Bp + 3 * 32);
    half8 q04 = *(const half8*)(Bp + 4 * 32);
    half8 q05 = *(const half8*)(Bp + 5 * 32);
    half8 q06 = *(const half8*)(Bp + 6 * 32);
    half8 q07 = *(const half8*)(Bp + 7 * 32);
    half8 q08 = *(const half8*)(Bp + 8 * 32);
    half8 q09 = *(const half8*)(Bp + 9 * 32);
    half8 q10 = *(const half8*)(Bp + 10 * 32);
    half8 q11 = *(const half8*)(Bp + 11 * 32);
    half8 q12 = *(const half8*)(Bp + 12 * 32);
    half8 q13 = *(const half8*)(Bp + 13 * 32);
    half8 q14 = *(const half8*)(Bp + 14 * 32);
    half8 q15 = *(const half8*)(Bp + 15 * 32);
    floatx4 p0 = floatx4{0.f, 0.f, 0.f, 0.f};
    floatx4 p1 = floatx4{0.f, 0.f, 0.f, 0.f};
    // two independent 8-deep chains, interleaved
    MFMA16(a00, q00, p0); MFMA16(a08, q08, p1);
    MFMA16(a01, q01, p0); MFMA16(a09, q09, p1);
    MFMA16(a02, q02, p0); MFMA16(a10, q10, p1);
    MFMA16(a03, q03, p0); MFMA16(a11, q11, p1);
    MFMA16(a04, q04, p0); MFMA16(a12, q12, p1);
    MFMA16(a05, q05, p0); MFMA16(a13, q13, p1);
    MFMA16(a06, q06, p0); MFMA16(a14, q14, p1);
    MFMA16(a07, q07, p0); MFMA16(a15, q15, p1);
    floatx4 ps = p0 + p1;                     // sum the two K-half accumulators
#pragma unroll
    for (int r = 0; r < 4; ++r)
      t2merge(v0[r], i0[r], v1[r], i1[r], ps[r], c0);

    if ((g & 31) == 31) {                     // per-512-col reduce + store, then reset
#pragma unroll
      for (int r = 0; r < 4; ++r) {
#pragma unroll
        for (int m = 1; m < 16; m <<= 1) {
          float ov0 = __shfl_xor(v0[r], m, 64);
          int oi0 = __shfl_xor(i0[r], m, 64);
          float ov1 = __shfl_xor(v1[r], m, 64);
          int oi1 = __shfl_xor(i1[r], m, 64);
          t2merge(v0[r], i0[r], v1[r], i1[r], ov0, oi0);
          t2merge(v0[r], i0[r], v1[r], i1[r], ov1, oi1);
        }
        if (cgrp == 0) {
          int grow = m0 + rgrp * 4 + r;
          float4 st;
          st.x = v0[r]; st.y = v1[r];
          st.z = __int_as_float(i0[r]); st.w = __int_as_float(i1[r]);
          top2[(size_t)grow * 16 + ne * 2 + (g >> 5)] = st;   // 16 col-512 slices per row
        }
        v0[r] = -3.4e38f; v1[r] = -3.4e38f;
        i0[r] = 0x7fffffff; i1[r] = 0x7fffffff;
      }
    }
    if ((g & 3) == 3) __builtin_amdgcn_s_barrier();   // raw barrier: re-converge for L1 reuse
  }
}

// ---------------- finalize: exact fp64 rescore of in-margin candidates, write indices ----
// top2 layout: [row][16] float4 (16 col-512 slices), each = (v0, v1, i0, i1).
__global__ __launch_bounds__(64) void k_finalize(const float4* __restrict__ top2,
                                                 const float* __restrict__ encT,
                                                 const float* __restrict__ cb,
                                                 const double* __restrict__ nrm,
                                                 float* __restrict__ idxf) {
  int row = blockIdx.x;
  int lane = threadIdx.x;
  float4 e0;
  if (lane < 16) {
    e0 = top2[(size_t)row * 16 + lane];
  } else {
    e0.x = -3.4e38f; e0.y = -3.4e38f;
    e0.z = __int_as_float(0x7fffffff); e0.w = __int_as_float(0x7fffffff);
  }
  float mx = e0.x;
#pragma unroll
  for (int m = 1; m < 64; m <<= 1) mx = fmaxf(mx, __shfl_xor(mx, m, 64));
  float thr = mx - MARGIN;
  float ev[8];
#pragma unroll
  for (int x = 0; x < 8; ++x) ev[x] = encT[(size_t)row * 512 + lane * 8 + x];
  double bs = -1e300;
  int bk = 0x7fffffff;
  float cv[2] = {e0.x, e0.y};
  int ci[2] = {__float_as_int(e0.z), __float_as_int(e0.w)};
#pragma unroll
  for (int j = 0; j < 2; ++j) {
    unsigned long long ball = __ballot(cv[j] >= thr);
    while (ball) {
      int src = __ffsll(ball) - 1;
      ball &= ball - 1;
      int k = __shfl(ci[j], src, 64);
      const float* crow = cb + (size_t)k * 512;
      double s = 0.0;
#pragma unroll
      for (int x = 0; x < 8; ++x) s += (double)ev[x] * (double)crow[lane * 8 + x];
#pragma unroll
      for (int m = 1; m < 64; m <<= 1) s += __shfl_xor(s, m, 64);
      double sc = s / nrm[k];
      if (sc > bs || (sc == bs && k < bk)) { bs = sc; bk = k; }
    }
  }
  if (lane == 0) idxf[row] = (float)bk;
}

// ---------------- gather: z_q / z_q_out = codebook[idx] (B,D,T-layout) * mask ----------------
__global__ __launch_bounds__(256) void k_gather(const float* __restrict__ cb,
                                                const float* __restrict__ idxf,
                                                const float* __restrict__ mask,
                                                float* __restrict__ zq,
                                                float* __restrict__ zqout) {
  int bid = blockIdx.x;
  int db = bid & 7, tb = (bid >> 3) & 31, b = bid >> 8;
  int d0 = db * 64, t0 = tb * 64;
  __shared__ float tile[64][65];
  __shared__ int kidx[64];
  __shared__ float mk[64];
  int tid = threadIdx.x, w = tid >> 6, lane = tid & 63;
  if (tid < 64) {
    kidx[tid] = (int)idxf[b * T_ + t0 + tid];
    mk[tid] = mask[b * T_ + t0 + tid];
  }
  __syncthreads();
#pragma unroll
  for (int it = 0; it < 16; ++it) {
    int tl = it * 4 + w;
    int k = kidx[tl];
    tile[lane][tl] = cb[(size_t)k * D_ + d0 + lane];       // coalesced cb row segment
  }
  __syncthreads();
#pragma unroll
  for (int it = 0; it < 16; ++it) {
    int dl = it * 4 + w;
    float v = tile[dl][lane] * mk[lane];
    size_t off = ((size_t)(b * D_ + d0 + dl)) * T_ + t0 + lane;  // coalesced along t
    zq[off] = v;
    zqout[off] = v;
  }
}

// ---------------- z_e = z (verbatim copy) ----------------
__global__ __launch_bounds__(256) void k_copy_ze(const float4* __restrict__ z4,
                                                 float4* __restrict__ o4) {
  size_t n4 = ZSZ / 4;
  for (size_t i = (size_t)blockIdx.x * 256 + threadIdx.x; i < n4; i += (size_t)gridDim.x * 256)
    o4[i] = z4[i];
}

extern "C" void kernel_launch(void* const* d_in, const int* in_sizes, int n_in,
                              void* d_out, int out_size, void* d_ws, size_t ws_size,
                              hipStream_t stream) {
  const float* z = (const float*)d_in[0];
  const float* mask = (const float*)d_in[1];
  const float* cb = (const float*)d_in[2];
  float* out = (float*)d_out;
  char* o = (char*)d_out;
  // ALL scratch lives inside d_out (100.7 MB); d_ws untouched.
  //   seg0 [0,      SEGB): final z_q      | staging: encTh (16.8M) + cbh (8.4M) + nrm (64K)
  //   seg1 [SEGB,  2SEGB): final z_e      | staging: top2 (16384 x 16 float4 = 4 MB)
  //   seg2 [2SEGB, 3SEGB): final z_q_out  | staging: encT f32 (exactly 33.55M)
  //   seg3 [3SEGB, ...  ): final indices (float; finalize writes, gather reads back)
  // Write order: prep(seg0,seg2) -> gemm(seg1) -> finalize(seg3) -> gather(seg0,seg2) -> copy(seg1)
  _Float16* encTh = (_Float16*)(o);                       // 16,777,216 B
  _Float16* cbh   = (_Float16*)(o + 16777216);            //  8,388,608 B
  double*   nrm   = (double*)(o + 25165824);              //     65,536 B  (< SEGB total)
  float4*   top2  = (float4*)(o + SEGB);                  //  4,194,304 B
  float*    encT  = (float*)(o + 2 * SEGB);               // 33,554,432 B
  float*    idxf  = out + 3 * ZSZ;                        // 16384 floats (final output 3)
  float*    zq    = out;                                  // final output 0
  float*    ze    = out + ZSZ;                            // final output 1
  float*    zqout = out + 2 * ZSZ;                        // final output 2

  k_prep_z<<<2048, 256, 0, stream>>>(z, encT, encTh);
  k_prep_cb<<<8192, 256, 0, stream>>>(cb, cbh, nrm);
  k_gemm_top2<<<2048, 256, 0, stream>>>(encTh, cbh, top2);
  k_finalize<<<16384, 64, 0, stream>>>(top2, encT, cb, nrm, idxf);
  k_gather<<<2048, 256, 0, stream>>>(cb, idxf, mask, zq, zqout);
  k_copy_ze<<<2048, 256, 0, stream>>>((const float4*)z, (float4*)ze);
}